// Round 4
// baseline (267.178 us; speedup 1.0000x reference)
//
#include <hip/hip_runtime.h>

#define IN_DIM 128
#define OUT_DIM 128
#define KERN 3
#define NCOL 384          // KERN * IN_DIM
#define BN_EPS 1e-5f
#define SLOPE 0.01f

typedef unsigned int uint;
typedef unsigned short ushort;
typedef __attribute__((ext_vector_type(8))) short short8;
typedef __attribute__((ext_vector_type(4))) float f32x4;

__device__ __forceinline__ ushort f32_to_bf16(float f) {
    uint b = __float_as_uint(f);
    return (ushort)((b + 0x7fffu + ((b >> 16) & 1u)) >> 16);
}
__device__ __forceinline__ uint pack_bf16x2(float lo, float hi) {
    return (uint)f32_to_bf16(lo) | ((uint)f32_to_bf16(hi) << 16);
}

// ---------------------------------------------------------------------------
// prep: region A zero counts+stats, region B h->bf16, region C weight permute
// Bt[o][c] = bf16(fc_w[i*384 + k*128 + o]),  c = k*128 + i
// ---------------------------------------------------------------------------
__global__ __launch_bounds__(256) void prep(
    int* __restrict__ zero_base, int nz,
    const float* __restrict__ h, ushort* __restrict__ hb, int total4,
    const float* __restrict__ W, ushort* __restrict__ Bt,
    int gA, int gB)
{
    const int b = blockIdx.x;
    if (b < gA) {
        const int i = b * 256 + threadIdx.x;
        if (i < nz) zero_base[i] = 0;
    } else if (b < gA + gB) {
        const int i = (b - gA) * 256 + threadIdx.x;
        if (i < total4) {
            const float4 v = *(const float4*)&h[(size_t)i * 4];
            ushort4 o;
            o.x = f32_to_bf16(v.x); o.y = f32_to_bf16(v.y);
            o.z = f32_to_bf16(v.z); o.w = f32_to_bf16(v.w);
            *(ushort4*)&hb[(size_t)i * 4] = o;
        }
    } else {
        const int idx = (b - gA - gB) * 256 + threadIdx.x;
        if (idx < 128 * NCOL) {
            const int o = idx / NCOL;
            const int c = idx - o * NCOL;
            const int i = c & 127;
            const int k = c >> 7;
            Bt[idx] = f32_to_bf16(W[(size_t)i * NCOL + (k << 7) + o]);
        }
    }
}

// ---------------------------------------------------------------------------
// 1. histogram of dst
// ---------------------------------------------------------------------------
__global__ __launch_bounds__(256) void hist_dst(
    const int* __restrict__ dst, int* __restrict__ counts, int E)
{
    const int e = blockIdx.x * 256 + threadIdx.x;
    if (e < E) atomicAdd(&counts[dst[e]], 1);
}

// ---------------------------------------------------------------------------
// 2. prefix sum: scan1 per-chunk sums; scan2 parallel scan of chunk sums;
//    scan3 intra-chunk scan -> row_start AND cursor (working copy)
// ---------------------------------------------------------------------------
#define SCHUNK 512

__global__ __launch_bounds__(256) void scan1(
    const int* __restrict__ counts, int* __restrict__ blocksum, int N)
{
    __shared__ int s[256];
    const int tid = threadIdx.x;
    const int base = blockIdx.x * SCHUNK;
    int v = 0;
    if (base + tid < N) v += counts[base + tid];
    if (base + 256 + tid < N) v += counts[base + 256 + tid];
    s[tid] = v;
    __syncthreads();
    for (int off = 128; off > 0; off >>= 1) {
        if (tid < off) s[tid] += s[tid + off];
        __syncthreads();
    }
    if (tid == 0) blocksum[blockIdx.x] = s[0];
}

__global__ __launch_bounds__(128) void scan2(
    const int* __restrict__ blocksum, int* __restrict__ chunk_off,
    int* __restrict__ row_start, int nch, int N, int E)
{
    __shared__ int s[128];
    const int t = threadIdx.x;
    const int v0 = (t < nch) ? blocksum[t] : 0;
    s[t] = v0;
    __syncthreads();
    #pragma unroll
    for (int off = 1; off < 128; off <<= 1) {
        const int v = (t >= off) ? s[t - off] : 0;
        __syncthreads();
        s[t] += v;
        __syncthreads();
    }
    if (t < nch) chunk_off[t] = s[t] - v0;   // exclusive
    if (t == 0) row_start[N] = E;
}

__global__ __launch_bounds__(512) void scan3(
    const int* __restrict__ counts, const int* __restrict__ chunk_off,
    int* __restrict__ row_start, int* __restrict__ cursor, int N)
{
    __shared__ int s[SCHUNK];
    const int tid = threadIdx.x;
    const int i = blockIdx.x * SCHUNK + tid;
    const int v0 = (i < N) ? counts[i] : 0;
    s[tid] = v0;
    __syncthreads();
    for (int off = 1; off < SCHUNK; off <<= 1) {
        int t = 0;
        if (tid >= off) t = s[tid - off];
        __syncthreads();
        s[tid] += t;
        __syncthreads();
    }
    if (i < N) {
        const int rs = chunk_off[blockIdx.x] + s[tid] - v0;
        row_start[i] = rs;
        cursor[i] = rs;
    }
}

// ---------------------------------------------------------------------------
// 3. per-edge: gaussian weights + scatter {w0,w1,w2,src} into dst-sorted slot
// ---------------------------------------------------------------------------
__global__ __launch_bounds__(256) void edge_prep(
    const float* __restrict__ pseudo, const int* __restrict__ src,
    const int* __restrict__ dst, const float* __restrict__ mu,
    const float* __restrict__ isg,
    int* __restrict__ cursor, float4* __restrict__ edata, int E)
{
    const int e = blockIdx.x * 256 + threadIdx.x;
    if (e >= E) return;
    const float2 p = *(const float2*)&pseudo[(size_t)e * 2];
    float w[KERN];
    #pragma unroll
    for (int k = 0; k < KERN; ++k) {
        const float dx = (p.x - mu[2 * k])     * isg[2 * k];
        const float dy = (p.y - mu[2 * k + 1]) * isg[2 * k + 1];
        w[k] = __expf(-0.5f * (dx * dx + dy * dy));
    }
    const int pos = atomicAdd(&cursor[dst[e]], 1);
    edata[pos] = make_float4(w[0], w[1], w[2], __int_as_float(src[e]));
}

// ---------------------------------------------------------------------------
// 4. FUSED aggregate + MFMA GEMM + BN-stat partials.
//    Block: 256 thr / 4 waves, BM=64 dst nodes.
//    Phase 1: wave w aggregates nodes w*16..w*16+15 into swizzled LDS As
//             As row r (768B): bf16 g[d, c], c = k*128 + ch, XOR ((r&7)<<4)
//    Phase 2: 3 chunks of BK=128: stream Bt chunk to Bs, 16x16x32 MFMA.
//    Epilogue: C write + per-channel sum/sumsq -> global stats (LDS reduce).
// ---------------------------------------------------------------------------
#define BM 64

__global__ __launch_bounds__(256) void agg_gemm(
    const ushort* __restrict__ hb, const float4* __restrict__ edata,
    const int* __restrict__ row_start, const ushort* __restrict__ Bt,
    float* __restrict__ C, float* __restrict__ stats, int M)
{
    __shared__ ushort As[BM * NCOL];    // 48 KB
    __shared__ ushort Bs[128 * 128];    // 32 KB   (total 80 KB -> 2 blocks/CU)

    const int tid = threadIdx.x;
    const int lane = tid & 63;
    const int wid = tid >> 6;
    const int n0 = blockIdx.x * BM;
    char* AsB = (char*)As;

    // ---- phase 1: aggregation ----
    const size_t hoff = (size_t)(lane << 1);
    for (int nn = 0; nn < 16; ++nn) {
        const int r = wid * 16 + nn;
        const int d = n0 + r;
        float a00 = 0.f, a01 = 0.f, a10 = 0.f, a11 = 0.f, a20 = 0.f, a21 = 0.f;
        if (d < M) {
            const int beg = row_start[d];
            const int end = row_start[d + 1];
            int i = beg;
            for (; i + 3 < end; i += 4) {
                const float4 e0 = edata[i];
                const float4 e1 = edata[i + 1];
                const float4 e2 = edata[i + 2];
                const float4 e3 = edata[i + 3];
                const uint u0 = *(const uint*)&hb[(size_t)__float_as_int(e0.w) * IN_DIM + hoff];
                const uint u1 = *(const uint*)&hb[(size_t)__float_as_int(e1.w) * IN_DIM + hoff];
                const uint u2 = *(const uint*)&hb[(size_t)__float_as_int(e2.w) * IN_DIM + hoff];
                const uint u3 = *(const uint*)&hb[(size_t)__float_as_int(e3.w) * IN_DIM + hoff];
                const float v0l = __uint_as_float(u0 << 16), v0h = __uint_as_float(u0 & 0xffff0000u);
                const float v1l = __uint_as_float(u1 << 16), v1h = __uint_as_float(u1 & 0xffff0000u);
                const float v2l = __uint_as_float(u2 << 16), v2h = __uint_as_float(u2 & 0xffff0000u);
                const float v3l = __uint_as_float(u3 << 16), v3h = __uint_as_float(u3 & 0xffff0000u);
                a00 += e0.x * v0l + e1.x * v1l + e2.x * v2l + e3.x * v3l;
                a01 += e0.x * v0h + e1.x * v1h + e2.x * v2h + e3.x * v3h;
                a10 += e0.y * v0l + e1.y * v1l + e2.y * v2l + e3.y * v3l;
                a11 += e0.y * v0h + e1.y * v1h + e2.y * v2h + e3.y * v3h;
                a20 += e0.z * v0l + e1.z * v1l + e2.z * v2l + e3.z * v3l;
                a21 += e0.z * v0h + e1.z * v1h + e2.z * v2h + e3.z * v3h;
            }
            for (; i < end; ++i) {
                const float4 e0 = edata[i];
                const uint u0 = *(const uint*)&hb[(size_t)__float_as_int(e0.w) * IN_DIM + hoff];
                const float v0l = __uint_as_float(u0 << 16), v0h = __uint_as_float(u0 & 0xffff0000u);
                a00 += e0.x * v0l; a01 += e0.x * v0h;
                a10 += e0.y * v0l; a11 += e0.y * v0h;
                a20 += e0.z * v0l; a21 += e0.z * v0h;
            }
        }
        const int sw = (r & 7) << 4;
        const int rb = r * 768;
        *(uint*)(AsB + rb + (((lane << 2))       ^ sw)) = pack_bf16x2(a00, a01);
        *(uint*)(AsB + rb + ((256 + (lane << 2)) ^ sw)) = pack_bf16x2(a10, a11);
        *(uint*)(AsB + rb + ((512 + (lane << 2)) ^ sw)) = pack_bf16x2(a20, a21);
    }
    __syncthreads();

    // ---- phase 2: MFMA over K=384 in 3 chunks of 128 ----
    const int wm = wid >> 1;
    const int wn = wid & 1;
    const int lrow = lane & 15;
    const int lk = (lane >> 4) << 4;    // byte offset of lane's 8 bf16
    f32x4 acc[2][4] = {};

    for (int kc = 0; kc < 3; ++kc) {
        #pragma unroll
        for (int p = 0; p < 8; ++p) {
            const int r = (tid >> 4) + p * 16;
            const int s = tid & 15;
            const uint4 v = *(const uint4*)&Bt[(size_t)r * NCOL + kc * 128 + s * 8];
            *(uint4*)((char*)Bs + r * 256 + ((s * 16) ^ ((r & 7) << 4))) = v;
        }
        __syncthreads();

        #pragma unroll
        for (int kk = 0; kk < 4; ++kk) {
            short8 af[2], bf[4];
            #pragma unroll
            for (int i = 0; i < 2; ++i) {
                const int rr = wm * 32 + i * 16 + lrow;
                af[i] = *(const short8*)(AsB + rr * 768 +
                        ((kc * 256 + kk * 64 + lk) ^ ((rr & 7) << 4)));
            }
            #pragma unroll
            for (int j = 0; j < 4; ++j) {
                const int o = wn * 64 + j * 16 + lrow;
                bf[j] = *(const short8*)((char*)Bs + o * 256 +
                        ((kk * 64 + lk) ^ ((o & 7) << 4)));
            }
            #pragma unroll
            for (int i = 0; i < 2; ++i)
                #pragma unroll
                for (int j = 0; j < 4; ++j)
                    acc[i][j] = __builtin_amdgcn_mfma_f32_16x16x32_bf16(
                        af[i], bf[j], acc[i][j], 0, 0, 0);
        }
        __syncthreads();
    }

    // ---- epilogue: C write + BN stats ----
    float s[4] = {0.f, 0.f, 0.f, 0.f};
    float ss[4] = {0.f, 0.f, 0.f, 0.f};
    #pragma unroll
    for (int i = 0; i < 2; ++i) {
        #pragma unroll
        for (int rr = 0; rr < 4; ++rr) {
            const int row = n0 + wm * 32 + i * 16 + (lane >> 4) * 4 + rr;
            if (row < M) {
                #pragma unroll
                for (int j = 0; j < 4; ++j) {
                    const float v = acc[i][j][rr];
                    C[(size_t)row * OUT_DIM + wn * 64 + j * 16 + lrow] = v;
                    s[j] += v;
                    ss[j] += v * v;
                }
            }
        }
    }
    float* sred = (float*)As;           // reuse As space (all reads done)
    sred[tid] = 0.f;
    __syncthreads();
    #pragma unroll
    for (int j = 0; j < 4; ++j) {
        const int col = wn * 64 + j * 16 + lrow;
        atomicAdd(&sred[col], s[j]);
        atomicAdd(&sred[128 + col], ss[j]);
    }
    __syncthreads();
    if (tid < 256) atomicAdd(&stats[tid], sred[tid]);
}

// ---------------------------------------------------------------------------
// 5. finalize: BN (bias cancels inside BN), leaky_relu, residual. In-place.
// ---------------------------------------------------------------------------
__global__ __launch_bounds__(256) void finalize(
    float* __restrict__ out, const float* __restrict__ h,
    const float* __restrict__ stats, const float* __restrict__ gamma,
    const float* __restrict__ beta, int total4, float invN)
{
    const int idx = blockIdx.x * 256 + threadIdx.x;
    if (idx >= total4) return;
    const int i4 = idx * 4;
    const int o4 = i4 & 127;

    float4 a  = *(const float4*)&out[i4];
    const float4 hh = *(const float4*)&h[i4];
    float r[4] = {a.x, a.y, a.z, a.w};
    const float hv[4] = {hh.x, hh.y, hh.z, hh.w};
    float res[4];
    #pragma unroll
    for (int j = 0; j < 4; ++j) {
        const int o = o4 + j;
        const float mean = stats[o] * invN;
        const float var = stats[128 + o] * invN - mean * mean;
        float x = (r[j] - mean) * rsqrtf(var + BN_EPS) * gamma[o] + beta[o];
        x = x > 0.f ? x : SLOPE * x;
        res[j] = x + hv[j];
    }
    *(float4*)&out[i4] = make_float4(res[0], res[1], res[2], res[3]);
}

// ---------------------------------------------------------------------------
extern "C" void kernel_launch(void* const* d_in, const int* in_sizes, int n_in,
                              void* d_out, int out_size, void* d_ws, size_t ws_size,
                              hipStream_t stream)
{
    const float* h      = (const float*)d_in[0];
    const float* pseudo = (const float*)d_in[1];
    const int*   src    = (const int*)d_in[2];
    const int*   dst    = (const int*)d_in[3];
    const float* fc_w   = (const float*)d_in[4];
    const float* mu     = (const float*)d_in[5];
    const float* isg    = (const float*)d_in[6];
    // d_in[7] = bias: cancels exactly inside BatchNorm -> unused
    const float* gamma  = (const float*)d_in[8];
    const float* beta   = (const float*)d_in[9];

    const int N = in_sizes[0] / IN_DIM;   // 50000
    const int E = in_sizes[2];            // 800000

    // workspace layout
    char* w = (char*)d_ws;
    size_t off = 0;
    float4* edata = (float4*)(w + off);  off += (size_t)E * 16;                 // 12.8 MB
    ushort* hb    = (ushort*)(w + off);  off += (size_t)N * IN_DIM * 2;         // 12.8 MB
    ushort* Bt    = (ushort*)(w + off);  off += (size_t)128 * NCOL * 2;         // 96 KB
    off = (off + 255) & ~(size_t)255;
    int* counts    = (int*)(w + off);    off += (size_t)N * 4;
    float* stats   = (float*)(w + off);  off += 256 * 4;    // counts..stats contiguous (zeroed together)
    off = (off + 255) & ~(size_t)255;
    int* row_start = (int*)(w + off);    off += ((size_t)N + 1) * 4;
    off = (off + 255) & ~(size_t)255;
    int* cursor    = (int*)(w + off);    off += (size_t)N * 4;
    off = (off + 255) & ~(size_t)255;
    int* blocksum  = (int*)(w + off);    off += 128 * 4;
    int* chunk_off = (int*)(w + off);    off += 128 * 4;

    const int nch = (N + SCHUNK - 1) / SCHUNK;   // 98

    // fused prep: zero counts+stats | h->bf16 | weight permute
    const int nz = N + 256;
    const int total4 = N * IN_DIM / 4;
    const int gA = (nz + 255) / 256;
    const int gB = (total4 + 255) / 256;
    const int gC = (128 * NCOL + 255) / 256;
    prep<<<gA + gB + gC, 256, 0, stream>>>(counts, nz, h, hb, total4,
                                           fc_w, Bt, gA, gB);

    // CSR build
    hist_dst<<<(E + 255) / 256, 256, 0, stream>>>(dst, counts, E);
    scan1<<<nch, 256, 0, stream>>>(counts, blocksum, N);
    scan2<<<1, 128, 0, stream>>>(blocksum, chunk_off, row_start, nch, N, E);
    scan3<<<nch, 512, 0, stream>>>(counts, chunk_off, row_start, cursor, N);
    edge_prep<<<(E + 255) / 256, 256, 0, stream>>>(pseudo, src, dst, mu, isg,
                                                   cursor, edata, E);

    // fused aggregate + GEMM (+BN stats) -> agg in d_out
    float* agg = (float*)d_out;
    agg_gemm<<<(N + BM - 1) / BM, 256, 0, stream>>>(hb, edata, row_start, Bt,
                                                    agg, stats, N);

    // BN + leaky_relu + residual
    const int total = N * OUT_DIM;
    finalize<<<(total / 4 + 255) / 256, 256, 0, stream>>>(
        agg, h, stats, gamma, beta, total / 4, 1.0f / (float)N);
}